// Round 13
// baseline (231.609 us; speedup 1.0000x reference)
//
#include <hip/hip_runtime.h>
#include <math.h>

#define Bn 16
#define Nn 1024
#define Dn 128

typedef unsigned short ushort;
typedef unsigned long long u64;
typedef short short8 __attribute__((ext_vector_type(8)));
typedef float f32x4 __attribute__((ext_vector_type(4)));
typedef ushort us8 __attribute__((ext_vector_type(8)));
typedef ushort us4 __attribute__((ext_vector_type(4)));

__device__ __forceinline__ ushort f2bf(float f) {
    unsigned u = __float_as_uint(f);
    u += 0x7fff + ((u >> 16) & 1);           // RTN-even
    return (ushort)(u >> 16);
}
__device__ __forceinline__ float bf2f(ushort s) {
    return __uint_as_float(((unsigned)s) << 16);
}

// ---- async global->LDS staging (m97 path). 16B/lane, LDS dst = uniform base + lane*16.
#if defined(__has_builtin)
#if __has_builtin(__builtin_amdgcn_global_load_lds)
#define HAVE_GLL 1
#endif
#endif
#ifndef HAVE_GLL
#define HAVE_GLL 0
#endif

typedef __attribute__((address_space(1))) void as1_t;
typedef __attribute__((address_space(3))) void as3_t;

__device__ __forceinline__ void stage_group(const void* gbase, void* lbase, int lane) {
#if HAVE_GLL
    __builtin_amdgcn_global_load_lds((as1_t*)((const char*)gbase + lane * 16),
                                     (as3_t*)lbase, 16, 0, 0);
#else
    *(us8*)((char*)lbase + lane * 16) = *(const us8*)((const char*)gbase + lane * 16);
#endif
}

// Fragment layouts (us8 units of 16 B), tile = 16 rows:
//   h16f/hA16f: unit = rt_global*256 + kc*64 + m*4 + q     (kc 0..3)
//   Ef:         unit = ((b*64 + rt)*32 + kc)*64 + m*4 + q  (kc 0..31)
//   Tf:         unit = ((b*8  + nt)*32 + kc)*64 + m*4 + q
// bm ballot layout: bm[(row_global*4 + chunk)*4 + j], chunk=col>>8, j=col&3, bit=(col>>2)&63

// ================= K0: weight split + Z init + adj ballot-pack (fused) =================
__global__ __launch_bounds__(256) void k_ph0(const float* __restrict__ Ww,
                                             const float* __restrict__ A,
                                             const float* __restrict__ adj,
                                             ushort* __restrict__ Whi, ushort* __restrict__ Wlo,
                                             ushort* __restrict__ AThi, ushort* __restrict__ ATlo,
                                             float* __restrict__ Z, u64* __restrict__ bm) {
    int L = blockIdx.x, t = threadIdx.x;
    if (L < 64) {
        int i = L * 256 + t;
        float w = Ww[i];
        ushort wh = f2bf(w);
        Whi[i] = wh;
        Wlo[i] = f2bf(w - bf2f(wh));
        int e = i >> 7, d = i & 127;
        float a = A[d * Dn + e];
        ushort ah = f2bf(a);
        AThi[i] = ah;
        ATlo[i] = f2bf(a - bf2f(ah));
        Z[i] = (float)Nn;                          // non-edge exp(0) mass, m=0 shift
    }
    int gwv = L * 4 + (t >> 6);
    int lane = t & 63;
    #pragma unroll 4
    for (int it = 0; it < 16; ++it) {
        int pair = gwv * 16 + it;                  // (row,chunk), 65536 total
        const float* p = adj + (size_t)pair * 256 + lane * 4;
        float4 v = *(const float4*)p;
        u64 b0 = __ballot(v.x > 0.f);
        u64 b1 = __ballot(v.y > 0.f);
        u64 b2 = __ballot(v.z > 0.f);
        u64 b3 = __ballot(v.w > 0.f);
        if (lane == 0) {
            u64* d = bm + (size_t)pair * 4;
            d[0] = b0; d[1] = b1; d[2] = b2; d[3] = b3;
        }
    }
}

// ================= K1: h = xW^T+b ; hA = h@A ; fragment bf16 out; x LDS-staged =================
__global__ __launch_bounds__(256) void k_h(const float* __restrict__ x,
                                           const float* __restrict__ Wb,
                                           const ushort* __restrict__ Whi,
                                           const ushort* __restrict__ Wlo,
                                           const ushort* __restrict__ AThi,
                                           const ushort* __restrict__ ATlo,
                                           float* __restrict__ h,
                                           ushort* __restrict__ h16f,
                                           ushort* __restrict__ hA16f) {
    int I0 = blockIdx.x * 16;
    int t = threadIdx.x, w = t >> 6, lane = t & 63;
    int m = lane & 15, q = lane >> 4;

    __shared__ float xs[16][Dn + 4];
    __shared__ float hs[16][Dn + 4];
    __shared__ float has[16][Dn + 4];

    {   // coalesced x stage
        int r = t >> 4, c8 = (t & 15) * 8;
        const float* src = x + (size_t)(I0 + r) * Dn + c8;
        *(float4*)&xs[r][c8]     = *(const float4*)(src);
        *(float4*)&xs[r][c8 + 4] = *(const float4*)(src + 4);
    }
    __syncthreads();

    f32x4 acc0 = {0,0,0,0}, acc1 = {0,0,0,0};
    #pragma unroll
    for (int ks = 0; ks < 4; ++ks) {
        int k0 = q * 8 + ks * 32;
        float v[8]; short8 ahi, alo;
        *(float4*)(v)     = *(const float4*)(&xs[m][k0]);
        *(float4*)(v + 4) = *(const float4*)(&xs[m][k0 + 4]);
        #pragma unroll
        for (int j = 0; j < 8; ++j) {
            ushort hi = f2bf(v[j]);
            ahi[j] = (short)hi;
            alo[j] = (short)f2bf(v[j] - bf2f(hi));
        }
        #pragma unroll
        for (int nn = 0; nn < 2; ++nn) {
            int brow = (w * 2 + nn) * 16 + m;
            short8 bhi = __builtin_bit_cast(short8, ((const us8*)(Whi + (size_t)brow * Dn))[q + ks * 4]);
            short8 blo = __builtin_bit_cast(short8, ((const us8*)(Wlo + (size_t)brow * Dn))[q + ks * 4]);
            f32x4 acc = nn ? acc1 : acc0;
            acc = __builtin_amdgcn_mfma_f32_16x16x32_bf16(ahi, bhi, acc, 0, 0, 0);
            acc = __builtin_amdgcn_mfma_f32_16x16x32_bf16(alo, bhi, acc, 0, 0, 0);
            acc = __builtin_amdgcn_mfma_f32_16x16x32_bf16(ahi, blo, acc, 0, 0, 0);
            if (nn) acc1 = acc; else acc0 = acc;
        }
    }
    #pragma unroll
    for (int nn = 0; nn < 2; ++nn) {
        int col = (w * 2 + nn) * 16 + m;
        float bias = Wb[col];
        f32x4 acc = nn ? acc1 : acc0;
        #pragma unroll
        for (int r = 0; r < 4; ++r) {
            int rl = q * 4 + r;
            float hv = acc[r] + bias;
            h[(size_t)(I0 + rl) * Dn + col] = hv;
            hs[rl][col] = hv;
        }
    }
    __syncthreads();

    f32x4 bcc0 = {0,0,0,0}, bcc1 = {0,0,0,0};
    #pragma unroll
    for (int ks = 0; ks < 4; ++ks) {
        int k0 = q * 8 + ks * 32;
        float v[8]; short8 ahi, alo;
        *(float4*)(v)     = *(const float4*)(&hs[m][k0]);
        *(float4*)(v + 4) = *(const float4*)(&hs[m][k0 + 4]);
        #pragma unroll
        for (int j = 0; j < 8; ++j) {
            ushort hi = f2bf(v[j]);
            ahi[j] = (short)hi;
            alo[j] = (short)f2bf(v[j] - bf2f(hi));
        }
        #pragma unroll
        for (int nn = 0; nn < 2; ++nn) {
            int brow = (w * 2 + nn) * 16 + m;
            short8 bhi = __builtin_bit_cast(short8, ((const us8*)(AThi + (size_t)brow * Dn))[q + ks * 4]);
            short8 blo = __builtin_bit_cast(short8, ((const us8*)(ATlo + (size_t)brow * Dn))[q + ks * 4]);
            f32x4 acc = nn ? bcc1 : bcc0;
            acc = __builtin_amdgcn_mfma_f32_16x16x32_bf16(ahi, bhi, acc, 0, 0, 0);
            acc = __builtin_amdgcn_mfma_f32_16x16x32_bf16(alo, bhi, acc, 0, 0, 0);
            acc = __builtin_amdgcn_mfma_f32_16x16x32_bf16(ahi, blo, acc, 0, 0, 0);
            if (nn) bcc1 = acc; else bcc0 = acc;
        }
    }
    #pragma unroll
    for (int nn = 0; nn < 2; ++nn) {
        int col = (w * 2 + nn) * 16 + m;
        f32x4 acc = nn ? bcc1 : bcc0;
        #pragma unroll
        for (int r = 0; r < 4; ++r)
            has[q * 4 + r][col] = acc[r];
    }
    __syncthreads();

    {   // fragment-layout conversion
        int kc = t >> 6, mm = (t >> 2) & 15, qq = t & 3;
        int cb = kc * 32 + qq * 8;
        us8 oh, oa;
        #pragma unroll
        for (int e = 0; e < 8; ++e) {
            oh[e] = f2bf(hs[mm][cb + e]);
            oa[e] = f2bf(has[mm][cb + e]);
        }
        size_t U = (size_t)(I0 >> 4) * 256 + kc * 64 + mm * 4 + qq;
        ((us8*)h16f)[U]  = oh;
        ((us8*)hA16f)[U] = oa;
    }
}

// ================= K3: scores: J-side async-staged (32K), I-side register frags =================
__global__ __launch_bounds__(256, 4) void k_scores(const ushort* __restrict__ h16f,
                                                   const ushort* __restrict__ hA16f,
                                                   const u64* __restrict__ bm,
                                                   ushort* __restrict__ Ef,
                                                   float* __restrict__ Z) {
    int L = blockIdx.x;
    int b    = ((L & 7) << 1) | (L >> 11);        // XCD-grouped batches
    int tile = (L >> 3) & 255;
    int I0 = (tile >> 4) << 6;
    int J0 = (tile & 15) << 6;
    int t = threadIdx.x, wid = t >> 6, lane = t & 63;
    int m = lane & 15, q = lane >> 4;

    __shared__ __align__(16) char smem[33792];    // 32K J-stage (h_J, hA_J) + 1K cz
    float (*sc)[68] = (float(*)[68])smem;         // aliases J-stage after MFMA
    float (*cz)[64] = (float(*)[64])(smem + 32768);

    // issue async J-side staging: 32 x 1KB groups (g>>4: 0=h_J,1=hA_J; rt_l=(g>>2)&3; kk=g&3)
    {
        const char* hb = (const char*)h16f  + (size_t)b * 16384 * 16;
        const char* ab = (const char*)hA16f + (size_t)b * 16384 * 16;
        for (int g = wid; g < 32; g += 4) {
            int arr = g >> 4, rt_l = (g >> 2) & 3, kk = g & 3;
            int rbase = (J0 >> 4) + rt_l;
            const char* base = arr ? ab : hb;
            const char* gp = base + ((size_t)rbase * 256 + kk * 64) * 16;
            stage_group(gp, smem + g * 1024, lane);
        }
    }

    // I-side A fragments: direct coalesced register loads (R10-proven)
    const us8* Hf = (const us8*)h16f  + (size_t)b * 16384;
    const us8* Af = (const us8*)hA16f + (size_t)b * 16384;
    int off = m * 4 + q;
    int rtA = (I0 >> 4) + wid;
    us8 A1[4], A2[4];
    #pragma unroll
    for (int ks = 0; ks < 4; ++ks) {
        A1[ks] = Af[rtA * 256 + ks * 64 + off];    // hA_I
        A2[ks] = Hf[rtA * 256 + ks * 64 + off];    // h_I
    }
    __syncthreads();                               // drains async stage

    int off16 = off * 16;
    f32x4 acc[4] = {};
    #pragma unroll
    for (int ks = 0; ks < 4; ++ks) {
        short8 a1 = __builtin_bit_cast(short8, A1[ks]);
        short8 a2 = __builtin_bit_cast(short8, A2[ks]);
        #pragma unroll
        for (int nt = 0; nt < 4; ++nt) {
            short8 b1 = __builtin_bit_cast(short8, *(const us8*)(smem +         (nt * 4 + ks) * 1024 + off16)); // h_J
            short8 b2 = __builtin_bit_cast(short8, *(const us8*)(smem + 16384 + (nt * 4 + ks) * 1024 + off16)); // hA_J
            acc[nt] = __builtin_amdgcn_mfma_f32_16x16x32_bf16(a1, b1, acc[nt], 0, 0, 0);
            acc[nt] = __builtin_amdgcn_mfma_f32_16x16x32_bf16(a2, b2, acc[nt], 0, 0, 0);
        }
    }
    __syncthreads();                               // J-stage dead; alias as sc

    #pragma unroll
    for (int nt = 0; nt < 4; ++nt)
        #pragma unroll
        for (int r = 0; r < 4; ++r)
            sc[wid * 16 + q * 4 + r][nt * 16 + m] = acc[nt][r];
    __syncthreads();

    int row16 = t >> 4, c = t & 15;
    int bitc = ((J0 >> 2) & 63) + c;
    float colsum[4] = {0.f, 0.f, 0.f, 0.f};
    #pragma unroll
    for (int it = 0; it < 4; ++it) {
        int row = it * 16 + row16;
        const u64* wp = bm + ((size_t)(b * Nn + I0 + row) * 4 + (J0 >> 8)) * 4;
        u64 wj[4] = {wp[0], wp[1], wp[2], wp[3]};
        float s4[4];
        *(float4*)s4 = *(const float4*)(&sc[row][c * 4]);
        us4 e4;
        #pragma unroll
        for (int j = 0; j < 4; ++j) {
            float ex = __expf(s4[j]);
            bool on = (wj[j] >> bitc) & 1;
            e4[j] = f2bf(on ? ex : 0.f);
            colsum[j] += on ? (ex - 1.0f) : 0.f;
        }
        size_t U = ((((size_t)b * 64 + (I0 >> 4) + it) * 32 + (J0 >> 5) + (c >> 3)) * 16 + row16) * 4
                 + ((c & 7) >> 1);
        *(us4*)(Ef + U * 8 + (c & 1) * 4) = e4;
    }
    #pragma unroll
    for (int j = 0; j < 4; ++j) {
        colsum[j] += __shfl_xor(colsum[j], 16, 64);
        colsum[j] += __shfl_xor(colsum[j], 32, 64);
    }
    if (lane < 16) {
        #pragma unroll
        for (int j = 0; j < 4; ++j) cz[wid][lane * 4 + j] = colsum[j];
    }
    __syncthreads();
    if (t < 64) {
        float s = cz[0][t] + cz[1][t] + cz[2][t] + cz[3][t];
        atomicAdd(&Z[b * Nn + J0 + t], s);
    }
}

// ================= K4: Tf = fragment-layout (src/Z)^T =================
__global__ __launch_bounds__(256) void k_prep(const float* __restrict__ src,
                                              const float* __restrict__ Z,
                                              ushort* __restrict__ Tf) {
    int b = blockIdx.y;
    int j0 = blockIdx.x * 64;
    int t = threadIdx.x;
    __shared__ float ls[64][129];
    __shared__ float iz[64];
    if (t < 64) iz[t] = 1.0f / Z[b * Nn + j0 + t];
    __syncthreads();
    #pragma unroll
    for (int it = 0; it < 8; ++it) {
        int idx = it * 256 + t;
        int j = idx >> 5, k4 = (idx & 31) * 4;
        float4 v = *(const float4*)(src + ((size_t)b * Nn + j0 + j) * Dn + k4);
        float z = iz[j];
        ls[j][k4] = v.x * z; ls[j][k4 + 1] = v.y * z;
        ls[j][k4 + 2] = v.z * z; ls[j][k4 + 3] = v.w * z;
    }
    __syncthreads();
    int k = t & 127, half = t >> 7;
    us8 o[4];
    #pragma unroll
    for (int qq = 0; qq < 4; ++qq) {
        us8 tmp;
        #pragma unroll
        for (int e = 0; e < 8; ++e)
            tmp[e] = f2bf(ls[half * 32 + qq * 8 + e][k]);
        o[qq] = tmp;
    }
    size_t U = (((size_t)(k >> 4) * 32 + (j0 >> 5) + half) * 16 + (k & 15)) * 4;
    us8* dst = (us8*)(Tf + (size_t)b * 131072 + U * 8);
    dst[0] = o[0]; dst[1] = o[1]; dst[2] = o[2]; dst[3] = o[3];
}

// ================= K5: hop: 1024 blocks x 16 rows; E slab async-staged once (32K),
//                  barrier-free K-loop w/ direct B frags; R8-verified epilogue ============
__global__ __launch_bounds__(256, 4) void k_hop(const ushort* __restrict__ Ef,
                                                const ushort* __restrict__ Tf,
                                                const float* __restrict__ h,
                                                const float* __restrict__ Z,
                                                const float* __restrict__ gw,
                                                const float* __restrict__ gb,
                                                ushort* __restrict__ Tfn,
                                                float* __restrict__ out,
                                                int last) {
    int L = blockIdx.x;                           // 1024 blocks
    int b  = ((L & 7) << 1) | (L >> 9);           // XCD-grouped batches
    int rt = (L >> 3) & 63;                       // 16-row tile
    int I0 = rt << 4;
    int t = threadIdx.x, w = t >> 6, lane = t & 63;
    int m = lane & 15, q = lane >> 4;

    __shared__ __align__(16) char smem[33152];    // A slab 32K + red/cs/zz 384B
    float (*red)[16] = (float(*)[16])(smem + 32768);   // [4][16]
    float* cs = (float*)(smem + 32768 + 256);
    float* zz = (float*)(smem + 32768 + 320);
    ushort (*tt)[24] = (ushort(*)[24])smem;       // aliases A slab after K-loop (6KB)

    // stage the whole E row-slab: 32 x 1KB groups (group g = kc)
    {
        const char* Eb = (const char*)Ef + ((size_t)b * 64 + rt) * 32768;
        for (int g = w; g < 32; g += 4)
            stage_group(Eb + g * 1024, smem + g * 1024, lane);
    }

    int off = m * 4 + q;
    const us8* pB0 = (const us8*)Tf + ((size_t)b * 8 + 2 * w) * 2048 + off;
    const us8* pB1 = pB0 + 2048;                  // nt = 2w+1
    __syncthreads();                              // drains async stage

    const us8* As = (const us8*)smem;
    f32x4 acc0 = {0,0,0,0}, acc1 = {0,0,0,0};
    #pragma unroll 8
    for (int kc = 0; kc < 32; ++kc) {
        int o = kc * 64;
        short8 a  = __builtin_bit_cast(short8, As[o + off]);
        short8 b0 = __builtin_bit_cast(short8, pB0[o]);
        short8 b1 = __builtin_bit_cast(short8, pB1[o]);
        acc0 = __builtin_amdgcn_mfma_f32_16x16x32_bf16(a, b0, acc0, 0, 0, 0);
        acc1 = __builtin_amdgcn_mfma_f32_16x16x32_bf16(a, b1, acc1, 0, 0, 0);
    }

    // epilogue (R8-verified): col-split gate
    float gb0 = gb[0];
    int k0 = w * 32 + m, k1 = k0 + 16;
    float g0a = gw[k0], g0z = gw[Dn + k0], g1a = gw[k1], g1z = gw[Dn + k1];
    float hv0[4], hv1[4], az0[4], az1[4];
    size_t hbase = ((size_t)b * Nn + I0) * Dn;
    #pragma unroll
    for (int r = 0; r < 4; ++r) {
        int row = q * 4 + r;
        az0[r] = fmaxf(acc0[r], 0.f);
        az1[r] = fmaxf(acc1[r], 0.f);
        hv0[r] = h[hbase + (size_t)row * Dn + k0];
        hv1[r] = h[hbase + (size_t)row * Dn + k1];
        float gs = hv0[r] * g0a + az0[r] * g0z + hv1[r] * g1a + az1[r] * g1z;
        gs += __shfl_xor(gs, 1, 64);
        gs += __shfl_xor(gs, 2, 64);
        gs += __shfl_xor(gs, 4, 64);
        gs += __shfl_xor(gs, 8, 64);              // sum over 16 m-lanes
        if (m == 0) red[w][row] = gs;
    }
    __syncthreads();
    if (t < 16) {
        float v = red[0][t] + red[1][t] + red[2][t] + red[3][t];
        cs[t] = 1.0f / (1.0f + __expf(-(v + gb0)));
        zz[t] = 1.0f / Z[b * Nn + I0 + t];
    }
    __syncthreads();

    if (last) {
        #pragma unroll
        for (int r = 0; r < 4; ++r) {
            int row = q * 4 + r;
            float cc = cs[row];
            out[hbase + (size_t)row * Dn + k0] = cc * hv0[r] + (1.f - cc) * az0[r];
            out[hbase + (size_t)row * Dn + k1] = cc * hv1[r] + (1.f - cc) * az1[r];
        }
    } else {
        #pragma unroll
        for (int r = 0; r < 4; ++r) {
            int row = q * 4 + r;
            float cc = cs[row], iz = zz[row];
            tt[k0][row] = f2bf((cc * hv0[r] + (1.f - cc) * az0[r]) * iz);
            tt[k1][row] = f2bf((cc * hv1[r] + (1.f - cc) * az1[r]) * iz);
        }
        __syncthreads();
        // fragment-layout Tf write (R8-verified formula)
        int k = t >> 1, part = t & 1;
        size_t U = (((size_t)(k >> 4) * 32 + (I0 >> 5)) * 16 + (k & 15)) * 4
                 + ((I0 & 31) >> 3) + part;
        ((us8*)Tfn)[(size_t)b * 16384 + U] = *(const us8*)&tt[k][part * 8];
    }
}

extern "C" void kernel_launch(void* const* d_in, const int* in_sizes, int n_in,
                              void* d_out, int out_size, void* d_ws, size_t ws_size,
                              hipStream_t stream) {
    const float* x    = (const float*)d_in[0];   // [B,N,128]
    const float* adj  = (const float*)d_in[1];   // [B,N,N]
    const float* Ww   = (const float*)d_in[2];   // [128,128]
    const float* Wb   = (const float*)d_in[3];   // [128]
    const float* A    = (const float*)d_in[4];   // [128,128]
    const float* gw   = (const float*)d_in[5];   // [1,256]
    const float* gb   = (const float*)d_in[6];   // [1]
    float* out = (float*)d_out;                  // [B,N,128] f32

    char* ws = (char*)d_ws;
    float*  h    = (float*)(ws);                          // 8 MB f32
    ushort* Ta   = (ushort*)(ws + (8u << 20));            // 4 MB: h16f, then Tf buf A
    ushort* Tb   = (ushort*)(ws + (12u << 20));           // 4 MB: hA16f, then Tf buf B
    ushort* E    = (ushort*)(ws + (16u << 20));           // 32 MB (fragment layout)
    float*  Z    = (float*)(ws + (48u << 20));            // 64 KB
    ushort* Whi  = (ushort*)(ws + (48u << 20) + (64u << 10));
    ushort* Wlo  = (ushort*)(ws + (48u << 20) + (96u << 10));
    ushort* AThi = (ushort*)(ws + (48u << 20) + (128u << 10));
    ushort* ATlo = (ushort*)(ws + (48u << 20) + (160u << 10));
    u64*    bm   = (u64*)(ws + (48u << 20) + (192u << 10));  // 2 MB bitmask
    // total ~50.2 MB

    k_ph0   <<<1024, 256, 0, stream>>>(Ww, A, adj, Whi, Wlo, AThi, ATlo, Z, bm);
    k_h     <<<1024, 256, 0, stream>>>(x, Wb, Whi, Wlo, AThi, ATlo, h, Ta, Tb);
    k_scores<<<4096, 256, 0, stream>>>(Ta, Tb, bm, E, Z);
    k_prep  <<<dim3(16, Bn), 256, 0, stream>>>(h, Z, Ta);          // Tf0 = (h/Z)^T
    k_hop   <<<1024, 256, 0, stream>>>(E, Ta, h, Z, gw, gb, Tb, out, 0);
    k_hop   <<<1024, 256, 0, stream>>>(E, Tb, h, Z, gw, gb, Ta, out, 0);
    k_hop   <<<1024, 256, 0, stream>>>(E, Ta, h, Z, gw, gb, (ushort*)nullptr, out, 1);
}